// Round 3
// baseline (42.530 us; speedup 1.0000x reference)
//
#include <hip/hip_runtime.h>

// BernsteinSplineCouplingBlock: BATCH=65536, CHANNELS=64, SPLIT1=SPLIT2=32, DEGREE=10
// out[:, :32] = x[:, :32]
// s = x1 @ W.T + b  -> [B*32, 12]; spline(s, x2) -> out[:, 32:]
// GEMM via split-bf16 (hi+lo) 3-MFMA chain for ~f32 precision.

typedef short v8s  __attribute__((ext_vector_type(8)));  // 8 x bf16 (4 VGPRs)
typedef float f32x4 __attribute__((ext_vector_type(4)));

__device__ __forceinline__ short f2bf(float f) {
    union { float f; unsigned u; } v; v.f = f;
    return (short)((v.u + 0x7FFFu + ((v.u >> 16) & 1u)) >> 16);  // RNE
}

__device__ __forceinline__ float bf2f(short h) {
    union { unsigned u; float f; } v; v.u = ((unsigned)(unsigned short)h) << 16;
    return v.f;
}

__device__ __forceinline__ float softplus_f(float x) {
    return __logf(1.0f + __expf(x));   // s bounded (|s| < ~3): stable
}

__device__ __forceinline__ float sgn01(float x) {
    return (x > 0.f) ? 1.f : ((x < 0.f) ? -1.f : 0.f);
}

__global__ __launch_bounds__(256) void bern_spline_kernel(
    const float* __restrict__ x, const float* __restrict__ W,
    const float* __restrict__ bias, float* __restrict__ out)
{
    // W split hi/lo bf16, B-fragment order: [(k>>3)*3072 + out*8 + (k&7)]
    __shared__ short Wh[12288];          // 24 KB
    __shared__ short Wl[12288];          // 24 KB
    __shared__ float bl[384];            // 1.5 KB
    __shared__ float sl[4 * 16 * 100];   // per-wave 16 rows x (96+4pad) f32, 25.6 KB

    const int tid  = threadIdx.x;
    const int wave = tid >> 6;
    const int lane = tid & 63;
    const int block_row = blockIdx.x * 64;

    // ---- stage W (f32 -> bf16 hi + residual lo) and b ----
    for (int g = tid; g < 12288; g += 256) {
        const int o = g >> 5;        // W row (out index 0..383)
        const int k = g & 31;
        const float w = W[g];
        const short hi = f2bf(w);
        Wh[(k >> 3) * 3072 + o * 8 + (k & 7)] = hi;
        Wl[(k >> 3) * 3072 + o * 8 + (k & 7)] = f2bf(w - bf2f(hi));
    }
    for (int g = tid; g < 384; g += 256) bl[g] = bias[g];
    __syncthreads();

    // ---- x1 passthrough: out[row][0:32] = x[row][0:32] ----
    for (int i = tid; i < 512; i += 256) {
        const int r = i >> 3, q = i & 7;                   // 64 rows x 8 quads
        *(f32x4*)(out + (size_t)(block_row + r) * 64 + q * 4) =
            *(const f32x4*)(x + (size_t)(block_row + r) * 64 + q * 4);
    }

    // ---- A fragment: lane holds x1[row = l&15][k = (l>>4)*8 .. +7], hi+lo ----
    const int row16 = lane & 15;
    const int kq    = lane >> 4;
    const int arow  = block_row + wave * 16 + row16;
    const f32x4 a0 = *(const f32x4*)(x + (size_t)arow * 64 + kq * 8);
    const f32x4 a1 = *(const f32x4*)(x + (size_t)arow * 64 + kq * 8 + 4);
    v8s ah, al;
#pragma unroll
    for (int e = 0; e < 4; ++e) {
        const short h0 = f2bf(a0[e]);
        ah[e] = h0;     al[e] = f2bf(a0[e] - bf2f(h0));
        const short h1 = f2bf(a1[e]);
        ah[e + 4] = h1; al[e + 4] = f2bf(a1[e] - bf2f(h1));
    }

    float* swv = sl + wave * 1600;   // wave-private transpose buffer
    const f32x4 zero4 = {0.f, 0.f, 0.f, 0.f};

    for (int qt = 0; qt < 4; ++qt) {
        // ---- GEMM quarter: outs [qt*96, qt*96+96), 6 tiles x 3 MFMA ----
        f32x4 acc[6];
#pragma unroll
        for (int ot = 0; ot < 6; ++ot) {
            const int otg = qt * 6 + ot;
            const int boff = kq * 3072 + (otg * 16 + row16) * 8;
            const v8s bh = *(const v8s*)(Wh + boff);
            const v8s blo = *(const v8s*)(Wl + boff);
            f32x4 c = __builtin_amdgcn_mfma_f32_16x16x32_bf16(al, bh, zero4, 0, 0, 0);
            c = __builtin_amdgcn_mfma_f32_16x16x32_bf16(ah, blo, c, 0, 0, 0);
            acc[ot] = __builtin_amdgcn_mfma_f32_16x16x32_bf16(ah, bh, c, 0, 0, 0);
        }
        // C/D: row = (lane>>4)*4 + reg, col(out) = lane&15  -> scatter to LDS
#pragma unroll
        for (int ot = 0; ot < 6; ++ot)
#pragma unroll
            for (int r = 0; r < 4; ++r)
                swv[(kq * 4 + r) * 100 + ot * 16 + row16] = acc[ot][r];
        // wave-private region; same-wave DS ops complete in order

        // ---- spline: 16 rows x 8 channels = 128 pairs, 2 per lane ----
#pragma unroll
        for (int p = 0; p < 2; ++p) {
            const int idx = p * 64 + lane;
            const int cl  = idx & 7;          // local channel 0..7
            const int rr  = idx >> 3;         // row 0..15
            const int cg  = qt * 8 + cl;      // global channel 0..31

            const float* sp = swv + rr * 100 + cl * 12;
            const f32x4 s0 = *(const f32x4*)(sp);
            const f32x4 s1 = *(const f32x4*)(sp + 4);
            const f32x4 s2 = *(const f32x4*)(sp + 8);
            const f32x4 b0 = *(const f32x4*)(bl + cg * 12);
            const f32x4 b1 = *(const f32x4*)(bl + cg * 12 + 4);
            const f32x4 b2 = *(const f32x4*)(bl + cg * 12 + 8);

            float sv[12];
            sv[0] = s0[0] + b0[0]; sv[1]  = s0[1] + b0[1];
            sv[2] = s0[2] + b0[2]; sv[3]  = s0[3] + b0[3];
            sv[4] = s1[0] + b1[0]; sv[5]  = s1[1] + b1[1];
            sv[6] = s1[2] + b1[2]; sv[7]  = s1[3] + b1[3];
            sv[8] = s2[0] + b2[0]; sv[9]  = s2[1] + b2[1];
            sv[10] = s2[2] + b2[2]; sv[11] = s2[3] + b2[3];

            // cumsum(softplus) -> coeffs [0, cs...], normalized by last
            float cn[11];
            cn[0] = 0.f;
            float run = 0.f;
#pragma unroll
            for (int j = 0; j < 10; ++j) { run += softplus_f(sv[j]); cn[j + 1] = run; }
            const float inv = __fdividef(1.f, cn[10]);
#pragma unroll
            for (int j = 1; j <= 10; ++j) cn[j] *= inv;

            float wd = softplus_f(sv[10]);
            wd += 0.1f * sgn01(wd);
            float hg = sv[11];
            hg += 0.1f * sgn01(hg);

            const int rowg = block_row + wave * 16 + rr;
            const float xf = x[(size_t)rowg * 64 + 32 + cg];
            const float t   = __fdividef(xf, wd) + 0.5f;
            const float tcl = fminf(fmaxf(t, 0.f), 1.f);

            // deriv = DEGREE * deCasteljau(tc, diff(cn))  (10 coeffs, 9 iters)
            float d[10];
#pragma unroll
            for (int i = 0; i < 10; ++i) d[i] = cn[i + 1] - cn[i];
#pragma unroll
            for (int n = 9; n >= 1; --n) {
#pragma unroll
                for (int i = 0; i < n; ++i) d[i] += tcl * (d[i + 1] - d[i]);
            }
            const float deriv = 10.f * d[0];

            // ym = deCasteljau(tc, cn)  (11 coeffs, 10 iters)
#pragma unroll
            for (int n = 10; n >= 1; --n) {
#pragma unroll
                for (int i = 0; i < n; ++i) cn[i] += tcl * (cn[i + 1] - cn[i]);
            }
            const float ym = cn[0];

            float y = (t < 0.f) ? (t * deriv)
                    : ((t > 1.f) ? fmaf(t - 1.f, deriv, 1.f) : ym);
            y = (y - 0.5f) * hg;

            out[(size_t)rowg * 64 + 32 + cg] = y;
        }
    }
}

extern "C" void kernel_launch(void* const* d_in, const int* in_sizes, int n_in,
                              void* d_out, int out_size, void* d_ws, size_t ws_size,
                              hipStream_t stream) {
    const float* x = (const float*)d_in[0];
    const float* W = (const float*)d_in[1];
    const float* b = (const float*)d_in[2];
    float* out = (float*)d_out;
    // 65536 rows / 64 rows per block
    bern_spline_kernel<<<1024, 256, 0, stream>>>(x, W, b, out);
}

// Round 4
// 37.066 us; speedup vs baseline: 1.1474x; 1.1474x over previous
//
#include <hip/hip_runtime.h>

// BernsteinSplineCouplingBlock: BATCH=65536, CHANNELS=64, SPLIT1=SPLIT2=32, DEGREE=10
// out[:, :32] = x[:, :32]
// s = x1 @ W.T + b  -> [B*32, 12]; spline(s, x2) -> out[:, 32:]
// GEMM via split-bf16 (hi+lo) 3-MFMA chain for ~f32 precision.
// R4: W-split precomputed to d_ws by prep kernel (LDS 74.5->25.6 KB, no barriers),
//     deriv fused into main de Casteljau, deferred normalization.

typedef short v8s  __attribute__((ext_vector_type(8)));  // 8 x bf16 (4 VGPRs)
typedef float f32x4 __attribute__((ext_vector_type(4)));

__device__ __forceinline__ short f2bf(float f) {
    union { float f; unsigned u; } v; v.f = f;
    return (short)((v.u + 0x7FFFu + ((v.u >> 16) & 1u)) >> 16);  // RNE
}

__device__ __forceinline__ float bf2f(short h) {
    union { unsigned u; float f; } v; v.u = ((unsigned)(unsigned short)h) << 16;
    return v.f;
}

__device__ __forceinline__ float softplus_f(float x) {
    return __logf(1.0f + __expf(x));   // s bounded (|s| < ~2): stable
}

__device__ __forceinline__ float sgn01(float x) {
    return (x > 0.f) ? 1.f : ((x < 0.f) ? -1.f : 0.f);
}

// sv[0..9]: coeff_raw, sv[10]: width raw, sv[11]: height raw. xf: x2 value.
__device__ __forceinline__ float spline_eval(const float* sv, float xf) {
    // cumsum(softplus) -> unnormalized coeffs [0, cs...]
    float cn[11];
    cn[0] = 0.f;
    float run = 0.f;
#pragma unroll
    for (int j = 0; j < 10; ++j) { run += softplus_f(sv[j]); cn[j + 1] = run; }
    const float inv = __fdividef(1.f, run);

    const float wd = softplus_f(sv[10]) + 0.1f;   // softplus>0 => sign==+1
    float hg = sv[11];
    hg += 0.1f * sgn01(hg);

    const float t   = __fdividef(xf, wd) + 0.5f;
    const float tc  = fminf(fmaxf(t, 0.f), 1.f);

    // de Casteljau, stop at degree 1 (9 steps): b0=cn[0], b1=cn[1]
#pragma unroll
    for (int n = 10; n >= 2; --n) {
#pragma unroll
        for (int i = 0; i < n; ++i) cn[i] += tc * (cn[i + 1] - cn[i]);
    }
    const float db    = cn[1] - cn[0];
    const float deriv = 10.f * db * inv;              // B'(t), normalized
    const float ym    = fmaf(tc, db, cn[0]) * inv;    // B(t),  normalized

    float y = (t < 0.f) ? (t * deriv)
            : ((t > 1.f) ? fmaf(t - 1.f, deriv, 1.f) : ym);
    return (y - 0.5f) * hg;
}

// ---- prep: split W f32 -> bf16 hi/lo in B-fragment order ----
// frag layout: [(k>>3)*3072 + out*8 + (k&7)], hi at wsH, lo at wsH+12288
__global__ void prep_w(const float* __restrict__ W, short* __restrict__ wsH,
                       short* __restrict__ wsL) {
    const int g = blockIdx.x * 256 + threadIdx.x;
    if (g < 12288) {
        const int o = g >> 5;        // W row (out index 0..383)
        const int k = g & 31;
        const float w = W[g];
        const short hi = f2bf(w);
        const int off = (k >> 3) * 3072 + o * 8 + (k & 7);
        wsH[off] = hi;
        wsL[off] = f2bf(w - bf2f(hi));
    }
}

// ---- main: 64 rows/block, 4 waves, wave-private transpose LDS, no barriers ----
__global__ __launch_bounds__(256) void bern_spline_fast(
    const float* __restrict__ x, const short* __restrict__ wsH,
    const short* __restrict__ wsL, const float* __restrict__ bias,
    float* __restrict__ out)
{
    __shared__ float sl[4 * 16 * 100];   // per-wave 16 rows x (96+4pad) f32, 25.6 KB

    const int tid  = threadIdx.x;
    const int wave = tid >> 6;
    const int lane = tid & 63;
    const int block_row = blockIdx.x * 64;

    // x1 passthrough: out[row][0:32] = x[row][0:32]
    for (int i = tid; i < 512; i += 256) {
        const int r = i >> 3, q = i & 7;                   // 64 rows x 8 quads
        *(f32x4*)(out + (size_t)(block_row + r) * 64 + q * 4) =
            *(const f32x4*)(x + (size_t)(block_row + r) * 64 + q * 4);
    }

    // A fragment: lane holds x1[row = l&15][k = (l>>4)*8 .. +7], hi+lo
    const int row16 = lane & 15;
    const int kq    = lane >> 4;
    const int arow  = block_row + wave * 16 + row16;
    const f32x4 a0 = *(const f32x4*)(x + (size_t)arow * 64 + kq * 8);
    const f32x4 a1 = *(const f32x4*)(x + (size_t)arow * 64 + kq * 8 + 4);
    v8s ah, al;
#pragma unroll
    for (int e = 0; e < 4; ++e) {
        const short h0 = f2bf(a0[e]);
        ah[e] = h0;     al[e] = f2bf(a0[e] - bf2f(h0));
        const short h1 = f2bf(a1[e]);
        ah[e + 4] = h1; al[e + 4] = f2bf(a1[e] - bf2f(h1));
    }

    float* swv = sl + wave * 1600;   // wave-private transpose buffer
    const f32x4 zero4 = {0.f, 0.f, 0.f, 0.f};

    for (int qt = 0; qt < 4; ++qt) {
        // GEMM quarter: outs [qt*96, qt*96+96), 6 tiles x 3 MFMA (split-bf16)
        f32x4 acc[6];
#pragma unroll
        for (int ot = 0; ot < 6; ++ot) {
            const int otg  = qt * 6 + ot;
            const int boff = kq * 3072 + (otg * 16 + row16) * 8;
            const v8s bh  = *(const v8s*)(wsH + boff);   // global, L2-hot
            const v8s blo = *(const v8s*)(wsL + boff);
            f32x4 c = __builtin_amdgcn_mfma_f32_16x16x32_bf16(al, bh, zero4, 0, 0, 0);
            c = __builtin_amdgcn_mfma_f32_16x16x32_bf16(ah, blo, c, 0, 0, 0);
            acc[ot] = __builtin_amdgcn_mfma_f32_16x16x32_bf16(ah, bh, c, 0, 0, 0);
        }
        // C/D: row = (lane>>4)*4 + reg, col(out) = lane&15 -> scatter to LDS
#pragma unroll
        for (int ot = 0; ot < 6; ++ot)
#pragma unroll
            for (int r = 0; r < 4; ++r)
                swv[(kq * 4 + r) * 100 + ot * 16 + row16] = acc[ot][r];
        // wave-private region; same-wave DS ordering via compiler lgkmcnt

        // spline: 16 rows x 8 channels = 128 pairs, 2 per lane
#pragma unroll
        for (int p = 0; p < 2; ++p) {
            const int idx = p * 64 + lane;
            const int cl  = idx & 7;          // local channel 0..7
            const int rr  = idx >> 3;         // row 0..15
            const int cg  = qt * 8 + cl;      // global channel 0..31

            const float* sp = swv + rr * 100 + cl * 12;
            const f32x4 s0 = *(const f32x4*)(sp);
            const f32x4 s1 = *(const f32x4*)(sp + 4);
            const f32x4 s2 = *(const f32x4*)(sp + 8);
            const f32x4 b0 = *(const f32x4*)(bias + cg * 12);      // L1/L2-hot
            const f32x4 b1 = *(const f32x4*)(bias + cg * 12 + 4);
            const f32x4 b2 = *(const f32x4*)(bias + cg * 12 + 8);

            float sv[12];
            sv[0]  = s0[0] + b0[0]; sv[1]  = s0[1] + b0[1];
            sv[2]  = s0[2] + b0[2]; sv[3]  = s0[3] + b0[3];
            sv[4]  = s1[0] + b1[0]; sv[5]  = s1[1] + b1[1];
            sv[6]  = s1[2] + b1[2]; sv[7]  = s1[3] + b1[3];
            sv[8]  = s2[0] + b2[0]; sv[9]  = s2[1] + b2[1];
            sv[10] = s2[2] + b2[2]; sv[11] = s2[3] + b2[3];

            const int rowg = block_row + wave * 16 + rr;
            const float xf = x[(size_t)rowg * 64 + 32 + cg];
            out[(size_t)rowg * 64 + 32 + cg] = spline_eval(sv, xf);
        }
    }
}

// ---- fallback (R3 structure, known-pass): used only if ws is too small ----
__global__ __launch_bounds__(256) void bern_spline_fallback(
    const float* __restrict__ x, const float* __restrict__ W,
    const float* __restrict__ bias, float* __restrict__ out)
{
    __shared__ short Wh[12288];
    __shared__ short Wl[12288];
    __shared__ float bl[384];
    __shared__ float sl[4 * 16 * 100];

    const int tid  = threadIdx.x;
    const int wave = tid >> 6;
    const int lane = tid & 63;
    const int block_row = blockIdx.x * 64;

    for (int g = tid; g < 12288; g += 256) {
        const int o = g >> 5;
        const int k = g & 31;
        const float w = W[g];
        const short hi = f2bf(w);
        Wh[(k >> 3) * 3072 + o * 8 + (k & 7)] = hi;
        Wl[(k >> 3) * 3072 + o * 8 + (k & 7)] = f2bf(w - bf2f(hi));
    }
    for (int g = tid; g < 384; g += 256) bl[g] = bias[g];
    __syncthreads();

    for (int i = tid; i < 512; i += 256) {
        const int r = i >> 3, q = i & 7;
        *(f32x4*)(out + (size_t)(block_row + r) * 64 + q * 4) =
            *(const f32x4*)(x + (size_t)(block_row + r) * 64 + q * 4);
    }

    const int row16 = lane & 15;
    const int kq    = lane >> 4;
    const int arow  = block_row + wave * 16 + row16;
    const f32x4 a0 = *(const f32x4*)(x + (size_t)arow * 64 + kq * 8);
    const f32x4 a1 = *(const f32x4*)(x + (size_t)arow * 64 + kq * 8 + 4);
    v8s ah, al;
#pragma unroll
    for (int e = 0; e < 4; ++e) {
        const short h0 = f2bf(a0[e]);
        ah[e] = h0;     al[e] = f2bf(a0[e] - bf2f(h0));
        const short h1 = f2bf(a1[e]);
        ah[e + 4] = h1; al[e + 4] = f2bf(a1[e] - bf2f(h1));
    }

    float* swv = sl + wave * 1600;
    const f32x4 zero4 = {0.f, 0.f, 0.f, 0.f};

    for (int qt = 0; qt < 4; ++qt) {
        f32x4 acc[6];
#pragma unroll
        for (int ot = 0; ot < 6; ++ot) {
            const int otg = qt * 6 + ot;
            const int boff = kq * 3072 + (otg * 16 + row16) * 8;
            const v8s bh  = *(const v8s*)(Wh + boff);
            const v8s blo = *(const v8s*)(Wl + boff);
            f32x4 c = __builtin_amdgcn_mfma_f32_16x16x32_bf16(al, bh, zero4, 0, 0, 0);
            c = __builtin_amdgcn_mfma_f32_16x16x32_bf16(ah, blo, c, 0, 0, 0);
            acc[ot] = __builtin_amdgcn_mfma_f32_16x16x32_bf16(ah, bh, c, 0, 0, 0);
        }
#pragma unroll
        for (int ot = 0; ot < 6; ++ot)
#pragma unroll
            for (int r = 0; r < 4; ++r)
                swv[(kq * 4 + r) * 100 + ot * 16 + row16] = acc[ot][r];

#pragma unroll
        for (int p = 0; p < 2; ++p) {
            const int idx = p * 64 + lane;
            const int cl  = idx & 7;
            const int rr  = idx >> 3;
            const int cg  = qt * 8 + cl;

            const float* sp = swv + rr * 100 + cl * 12;
            const f32x4 s0 = *(const f32x4*)(sp);
            const f32x4 s1 = *(const f32x4*)(sp + 4);
            const f32x4 s2 = *(const f32x4*)(sp + 8);
            const f32x4 b0 = *(const f32x4*)(bl + cg * 12);
            const f32x4 b1 = *(const f32x4*)(bl + cg * 12 + 4);
            const f32x4 b2 = *(const f32x4*)(bl + cg * 12 + 8);

            float sv[12];
            sv[0]  = s0[0] + b0[0]; sv[1]  = s0[1] + b0[1];
            sv[2]  = s0[2] + b0[2]; sv[3]  = s0[3] + b0[3];
            sv[4]  = s1[0] + b1[0]; sv[5]  = s1[1] + b1[1];
            sv[6]  = s1[2] + b1[2]; sv[7]  = s1[3] + b1[3];
            sv[8]  = s2[0] + b2[0]; sv[9]  = s2[1] + b2[1];
            sv[10] = s2[2] + b2[2]; sv[11] = s2[3] + b2[3];

            const int rowg = block_row + wave * 16 + rr;
            const float xf = x[(size_t)rowg * 64 + 32 + cg];
            out[(size_t)rowg * 64 + 32 + cg] = spline_eval(sv, xf);
        }
    }
}

extern "C" void kernel_launch(void* const* d_in, const int* in_sizes, int n_in,
                              void* d_out, int out_size, void* d_ws, size_t ws_size,
                              hipStream_t stream) {
    const float* x = (const float*)d_in[0];
    const float* W = (const float*)d_in[1];
    const float* b = (const float*)d_in[2];
    float* out = (float*)d_out;

    if (d_ws != nullptr && ws_size >= 49152) {
        short* wsH = (short*)d_ws;
        short* wsL = wsH + 12288;
        prep_w<<<48, 256, 0, stream>>>(W, wsH, wsL);                     // 48 KB, L2-resident
        bern_spline_fast<<<1024, 256, 0, stream>>>(x, wsH, wsL, b, out); // 64 rows/block
    } else {
        bern_spline_fallback<<<1024, 256, 0, stream>>>(x, W, b, out);
    }
}